// Round 11
// baseline (127.958 us; speedup 1.0000x reference)
//
#include <hip/hip_runtime.h>

#define RANK 16
#define N 512

typedef float vfloat4 __attribute__((ext_vector_type(4)));

// Fill-style chip-wide sweep: at iteration j, the 2048 wave-pairs cooperatively
// write rows [2048j, 2048j+2048) — one dense 4 MB window marching through the
// 512 MB output. wave-pair wp owns b = wp&511 (fixed), a = 4j + (wp>>9).
__global__ __launch_bounds__(256, 4) void parafac_kernel(
    const float* __restrict__ f0,
    const float* __restrict__ f1,
    const float* __restrict__ f2,
    float* __restrict__ out)
{
    const int t    = threadIdx.x;
    const int wave = t >> 6;                     // 0..3
    const int lane = t & 63;
    const int wp   = blockIdx.x * 2 + (wave >> 1);   // global wave-pair 0..2047
    const int b    = wp & (N - 1);               // fixed b per wave-pair
    const int a0   = wp >> 9;                    // 0..3
    const int c4   = (wave & 1) * 256 + lane * 4;    // c-half per wave parity

    // f1 column b: 16 loop-invariant wave-uniform scalars in registers.
    float f1b[RANK];
#pragma unroll
    for (int k = 0; k < RANK; ++k) f1b[k] = f1[k * N + b];

    // f2 fragment: 16 x vfloat4 (64 VGPRs), loaded once.
    vfloat4 v[RANK];
#pragma unroll
    for (int k = 0; k < RANK; ++k)
        v[k] = *reinterpret_cast<const vfloat4*>(&f2[k * N + c4]);

    // Row r = 2048*j + wp; store address advances 4 MB per iteration.
    float* o = out + (size_t)wp * N + c4;

    int a = a0;
#pragma unroll 2
    for (int j = 0; j < 128; ++j) {
        vfloat4 acc = (vfloat4)(0.f);
#pragma unroll
        for (int k = 0; k < RANK; ++k) {
            const float pk = f0[k * N + a] * f1b[k];   // uniform load, L1-line reuse x4
            acc += pk * v[k];
        }
        *reinterpret_cast<vfloat4*>(o) = acc;           // 1 KB contiguous per wave
        o += (size_t)2048 * N;                          // next chip-wide window
        a += 4;
    }
}

extern "C" void kernel_launch(void* const* d_in, const int* in_sizes, int n_in,
                              void* d_out, int out_size, void* d_ws, size_t ws_size,
                              hipStream_t stream) {
    const float* f0 = (const float*)d_in[0];
    const float* f1 = (const float*)d_in[1];
    const float* f2 = (const float*)d_in[2];
    float* out = (float*)d_out;

    dim3 grid(1024);    // 2048 wave-pairs; 4 blocks/CU, 16 waves/CU
    dim3 block(256);
    parafac_kernel<<<grid, block, 0, stream>>>(f0, f1, f2, out);
}

// Round 12
// 100.107 us; speedup vs baseline: 1.2782x; 1.2782x over previous
//
#include <hip/hip_runtime.h>

#define RANK 16
#define N 512
#define BTILE 64
#define NBLK (N / BTILE)          // 8 b-tiles per a
#define NCHUNK (N * NBLK)         // 4096 (a, btile) chunks
#define CPB 4                     // chunks per block (consecutive -> 512 KB/block)
#define GRID (NCHUNK / CPB)       // 1024 blocks, all co-resident

typedef float vfloat4 __attribute__((ext_vector_type(4)));

__global__ __launch_bounds__(256) void parafac_kernel(
    const float* __restrict__ f0,
    const float* __restrict__ f1,
    const float* __restrict__ f2,
    float* __restrict__ out)
{
    __shared__ float pt[RANK][BTILE];   // k-major rank products, 4 KB

    const int t    = threadIdx.x;
    const int wave = t >> 6;            // 0..3
    const int lane = t & 63;
    const int rbase = (wave >> 1) * 32;     // 32-row strip per wave pair
    const int c4    = (wave & 1) * 256 + lane * 4;

    // f2 fragment resident in registers: 16 x float4 (64 VGPRs), loaded ONCE.
    vfloat4 v[RANK];
#pragma unroll
    for (int k = 0; k < RANK; ++k)
        v[k] = *reinterpret_cast<const vfloat4*>(&f2[k * N + c4]);

    // Staging indices (constant across chunks)
    const int sk  = t >> 4;             // 0..15
    const int sbi = (t & 15) * 4;       // 0..60

    for (int ci = 0; ci < CPB; ++ci) {
        const int cid = blockIdx.x * CPB + ci;   // consecutive output regions
        const int a   = cid / NBLK;
        const int b0  = (cid % NBLK) * BTILE;

        // Stage pt[k][bi] = f0[k][a] * f1[k][b0+bi]
        {
            const float s = f0[sk * N + a];
            const vfloat4 f1v = *reinterpret_cast<const vfloat4*>(&f1[sk * N + b0 + sbi]);
            *reinterpret_cast<vfloat4*>(&pt[sk][sbi]) = s * f1v;
        }
        __syncthreads();

        float* outa = out + ((size_t)a * N + b0) * N + c4;

        // 8 iterations x 4 rows; raw s_barrier keeps the 4 waves in lockstep so
        // the block's stores stay temporally dense (16 KB slices). No waitcnt:
        // pt is read-only within the chunk, stores need no drain.
#pragma unroll
        for (int it = 0; it < 8; ++it) {
            if (it != 0) __builtin_amdgcn_s_barrier();
            const int bb = rbase + it * 4;
            vfloat4 acc0 = (vfloat4)(0.f);
            vfloat4 acc1 = (vfloat4)(0.f);
            vfloat4 acc2 = (vfloat4)(0.f);
            vfloat4 acc3 = (vfloat4)(0.f);
#pragma unroll
            for (int k = 0; k < RANK; ++k) {
                const vfloat4 pk = *reinterpret_cast<const vfloat4*>(&pt[k][bb]); // broadcast
                const vfloat4 vk = v[k];
                acc0 += pk.x * vk;
                acc1 += pk.y * vk;
                acc2 += pk.z * vk;
                acc3 += pk.w * vk;
            }
            float* o = outa + (size_t)bb * N;
            *reinterpret_cast<vfloat4*>(o)         = acc0;
            *reinterpret_cast<vfloat4*>(o + N)     = acc1;
            *reinterpret_cast<vfloat4*>(o + 2 * N) = acc2;
            *reinterpret_cast<vfloat4*>(o + 3 * N) = acc3;
        }
        __syncthreads();   // pt reused next chunk
    }
}

extern "C" void kernel_launch(void* const* d_in, const int* in_sizes, int n_in,
                              void* d_out, int out_size, void* d_ws, size_t ws_size,
                              hipStream_t stream) {
    const float* f0 = (const float*)d_in[0];
    const float* f1 = (const float*)d_in[1];
    const float* f2 = (const float*)d_in[2];
    float* out = (float*)d_out;

    dim3 grid(GRID);    // 1024 blocks
    dim3 block(256);
    parafac_kernel<<<grid, block, 0, stream>>>(f0, f1, f2, out);
}